// Round 6
// baseline (1659.027 us; speedup 1.0000x reference)
//
#include <hip/hip_runtime.h>
#include <math.h>

#define T_LEN 24
#define NUU 2000
#define NLL 5000
#define NE 40000
#define CH 128
#define NH 4
#define HD 32
#define TCHUNK 8

typedef __attribute__((ext_vector_type(8))) short short8;
typedef __attribute__((ext_vector_type(4))) float f32x4;

static inline int cdiv(int a, int b) { return (a + b - 1) / b; }

__device__ __forceinline__ unsigned short f2bf(float x) {
    unsigned u = __float_as_uint(x);
    unsigned r = (u + 0x7fff + ((u >> 16) & 1)) >> 16;  // RNE
    return (unsigned short)r;
}
__device__ __forceinline__ float bf2f(unsigned short h) {
    return __uint_as_float(((unsigned)h) << 16);
}
__device__ __forceinline__ float2 bf2x(unsigned u) {
    float2 r;
    r.x = __uint_as_float(u << 16);
    r.y = __uint_as_float(u & 0xffff0000u);
    return r;
}

// ---------------- CSR build ----------------
__global__ void fill_zero_int(int* __restrict__ p, int n) {
    int i = blockIdx.x * blockDim.x + threadIdx.x;
    if (i < n) p[i] = 0;
}

__global__ void histo_kernel(const int* __restrict__ dst, int* __restrict__ deg, int n) {
    int idx = blockIdx.x * blockDim.x + threadIdx.x;
    if (idx >= T_LEN * NE) return;
    int t = idx / NE;
    atomicAdd(&deg[t * n + dst[idx]], 1);
}

// scan: writes both off (inclusive shifted) and cur (exclusive prefix, the running cursor)
__global__ __launch_bounds__(256) void scan_off(const int* __restrict__ deg, int* __restrict__ offo,
                                                int* __restrict__ cur, int n) {
    __shared__ int part[256];
    int t = blockIdx.x, tid = threadIdx.x;
    int items = (n + 255) / 256;
    int start = tid * items, end = min(start + items, n);
    const int* dt = deg + t * n;
    int s = 0;
    for (int i = start; i < end; ++i) s += dt[i];
    part[tid] = s;
    __syncthreads();
    for (int d = 1; d < 256; d <<= 1) {
        int v = (tid >= d) ? part[tid - d] : 0;
        __syncthreads();
        part[tid] += v;
        __syncthreads();
    }
    int run = part[tid] - s;  // exclusive prefix
    int* ot = offo + t * (n + 1);
    int* ct = cur + t * n;
    if (tid == 0) ot[0] = 0;
    for (int i = start; i < end; ++i) {
        ct[i] = run;
        run += dt[i];
        ot[i + 1] = run;
    }
}

// scatter src value directly into dst-sorted position (merged scatter_perm + src_sorted)
__global__ void scatter_src(const int* __restrict__ dst, const int* __restrict__ src,
                            int* __restrict__ cur, int* __restrict__ ssrc, int n) {
    int idx = blockIdx.x * blockDim.x + threadIdx.x;
    if (idx >= T_LEN * NE) return;
    int t = idx / NE;
    int d = dst[idx];
    int pos = atomicAdd(&cur[t * n + d], 1);
    ssrc[(size_t)t * NE + pos] = src[idx];
}

// ---------------- fused relation weights (f32) ----------------
__global__ __launch_bounds__(256) void build_fused(
    const float* __restrict__ w, const float* __restrict__ b,
    const float* __restrict__ ra, const float* __restrict__ rm,
    float* __restrict__ Wf, float* __restrict__ bf) {
    int idx = blockIdx.x * 256 + threadIdx.x;
    if (idx >= 128 * 384) return;
    int c = idx / 384, col = idx - c * 384;
    if (col < 128) {
        Wf[c * 384 + col] = w[16384 + c * 128 + col];
        if (c == 0) bf[col] = b[128 + col];
    } else {
        int sec = (col - 128) >> 7;
        int hc = (col - 128) & 127;
        int h = hc >> 5, e2 = hc & 31;
        const float* A = (sec == 0 ? ra : rm) + h * 1024;
        const float* wsrc = w + (sec == 0 ? 0 : 2) * 16384;
        const float* bsrc = b + (sec == 0 ? 0 : 2) * 128;
        float s = 0.f, sb = 0.f;
#pragma unroll
        for (int d = 0; d < 32; ++d) {
            float a = A[d * 32 + e2];
            s += wsrc[c * 128 + h * 32 + d] * a;
            sb += bsrc[h * 32 + d] * a;
        }
        Wf[c * 384 + col] = s;
        if (c == 0) bf[col] = sb;
    }
}

// ---------------- B prep: split f32 W[128][N] into fragment-ready bf16 hi/lo ----------------
__global__ void bprep_kernel(const float* __restrict__ W, unsigned short* __restrict__ prep, int N) {
    int idx = blockIdx.x * blockDim.x + threadIdx.x;
    if (idx >= 128 * N) return;
    int k = idx / N, n = idx - k * N;
    float v = W[idx];
    unsigned short hi = f2bf(v);
    unsigned short lo = f2bf(v - bf2f(hi));
    int nt = n >> 6, nl = n & 63;
    size_t base = (size_t)nt * 16384 + (size_t)nl * 128 + k;
    prep[base] = hi;
    prep[base + 8192] = lo;
}

// ---------------- MFMA GEMM: C = epi( A[M,128] @ W[128,N] + bias ) ----------------
// split-bf16 3-term. BM=128, BN=64, 4 waves (2x2). XCD-chunked bijective block swizzle (T1/m204)
// so all BN-tiles of consecutive BM-tiles land on the same XCD -> A stays L2-resident.
// EPI: 0 plain f32; 1 relu f32; 2 skip-blend f32; 3 qkm-split (q f32 stride128, km bf16 stride256)
template <bool GATHER, int EPI>
__global__ __launch_bounds__(256) void gemm_mfma(
    const float* __restrict__ A, const int* __restrict__ ids,
    const unsigned short* __restrict__ prep, const float* __restrict__ bias,
    float* __restrict__ C, const float* __restrict__ Xold,
    const float* __restrict__ skipPtr, unsigned short* __restrict__ km,
    int M, int NC) {
    __shared__ __align__(16) char smem[65536];  // Ah [128][256B] + Al at +32768, XOR-swizzled

    const int tid = threadIdx.x;
    const int lane = tid & 63;
    const int wid_w = tid >> 6;
    const int wm = wid_w >> 1, wn = wid_w & 1;
    const int l15 = lane & 15, l4 = lane >> 4;

    // bijective XCD-chunked swizzle
    const int nx = gridDim.x, ny = gridDim.y;
    int flat = blockIdx.y * nx + blockIdx.x;
    int nwg = nx * ny;
    int q = nwg >> 3, r = nwg & 7;
    int xcd = flat & 7, rank = flat >> 3;
    int wgid = (xcd < r ? xcd * (q + 1) : r * (q + 1) + (xcd - r) * q) + rank;
    const int m0 = (wgid / ny) * 128;
    const int n0 = (wgid % ny) * 64;

    const unsigned short* bp = prep + (size_t)(wgid % ny) * 16384;
    short8 bh[2][4], bl[2][4];
#pragma unroll
    for (int nf = 0; nf < 2; ++nf) {
        int ncol = wn * 32 + nf * 16 + l15;
#pragma unroll
        for (int ks = 0; ks < 4; ++ks) {
            size_t off = (size_t)ncol * 128 + ks * 32 + l4 * 8;
            bh[nf][ks] = *(const short8*)(bp + off);
            bl[nf][ks] = *(const short8*)(bp + 8192 + off);
        }
    }

#pragma unroll
    for (int i = 0; i < 16; ++i) {
        int flat2 = i * 256 + tid;
        int rr = flat2 >> 5, c4 = flat2 & 31;
        int gr = m0 + rr;
        if (gr >= M) gr = M - 1;
        int arow = GATHER ? ids[gr] : gr;
        float4 v = *(const float4*)(A + (size_t)arow * 128 + c4 * 4);
        unsigned short h0 = f2bf(v.x), h1 = f2bf(v.y), h2 = f2bf(v.z), h3 = f2bf(v.w);
        unsigned short q0 = f2bf(v.x - bf2f(h0)), q1 = f2bf(v.y - bf2f(h1));
        unsigned short q2 = f2bf(v.z - bf2f(h2)), q3 = f2bf(v.w - bf2f(h3));
        uint2 hp, lp;
        hp.x = (unsigned)h0 | ((unsigned)h1 << 16);
        hp.y = (unsigned)h2 | ((unsigned)h3 << 16);
        lp.x = (unsigned)q0 | ((unsigned)q1 << 16);
        lp.y = (unsigned)q2 | ((unsigned)q3 << 16);
        int off = rr * 256 + ((c4 * 8) ^ ((rr & 7) << 4));
        *(uint2*)(smem + off) = hp;
        *(uint2*)(smem + 32768 + off) = lp;
    }
    __syncthreads();

    f32x4 acc[4][2];
#pragma unroll
    for (int m = 0; m < 4; ++m)
#pragma unroll
        for (int nf = 0; nf < 2; ++nf) acc[m][nf] = (f32x4)0.f;

#pragma unroll
    for (int ks = 0; ks < 4; ++ks) {
        short8 ah[4], al[4];
#pragma unroll
        for (int m = 0; m < 4; ++m) {
            int row = wm * 64 + m * 16 + l15;
            int off = row * 256 + ((ks * 64 + l4 * 16) ^ ((row & 7) << 4));
            ah[m] = *(const short8*)(smem + off);
            al[m] = *(const short8*)(smem + 32768 + off);
        }
#pragma unroll
        for (int m = 0; m < 4; ++m)
#pragma unroll
            for (int nf = 0; nf < 2; ++nf) {
                acc[m][nf] = __builtin_amdgcn_mfma_f32_16x16x32_bf16(al[m], bh[nf][ks], acc[m][nf], 0, 0, 0);
                acc[m][nf] = __builtin_amdgcn_mfma_f32_16x16x32_bf16(ah[m], bl[nf][ks], acc[m][nf], 0, 0, 0);
                acc[m][nf] = __builtin_amdgcn_mfma_f32_16x16x32_bf16(ah[m], bh[nf][ks], acc[m][nf], 0, 0, 0);
            }
    }

    float g = 0.f;
    if (EPI == 2) g = 1.f / (1.f + expf(-skipPtr[0]));
    float bias_v[2];
#pragma unroll
    for (int nf = 0; nf < 2; ++nf) bias_v[nf] = bias[n0 + wn * 32 + nf * 16 + l15];

#pragma unroll
    for (int m = 0; m < 4; ++m) {
#pragma unroll
        for (int nf = 0; nf < 2; ++nf) {
            int gc = n0 + wn * 32 + nf * 16 + l15;
#pragma unroll
            for (int i = 0; i < 4; ++i) {
                int gr = m0 + wm * 64 + m * 16 + l4 * 4 + i;
                if (gr >= M) continue;
                float x = acc[m][nf][i] + bias_v[nf];
                if (EPI == 1) x = fmaxf(x, 0.f);
                if (EPI == 2) {
                    float xo = Xold[(size_t)gr * NC + gc];
                    x = g * x + (1.f - g) * xo;
                }
                if (EPI == 3) {
                    if (gc < 128) C[(size_t)gr * 128 + gc] = x;
                    else km[(size_t)gr * 256 + (gc - 128)] = f2bf(x);
                } else {
                    C[(size_t)gr * NC + gc] = x;
                }
            }
        }
    }
}

// ---------------- edge aggregation: bf16 k/m gather, online softmax, fused gelu ----------------
// 8 slots per (t_local, dst_node, head); lane bits[1:0]=head, [4:2]=slot; butterfly xor {4,8,16}.
__global__ __launch_bounds__(256) void agg_edges(
    const float* __restrict__ qD,            // [TCHUNK*nDst, 128] f32
    const unsigned short* __restrict__ kmS,  // [TCHUNK*nSrc, 256] bf16: k at 0, m at 128
    const int* __restrict__ off,             // [T_LEN, nDst+1]
    const int* __restrict__ ssrc,            // [T_LEN, NE] dst-sorted src ids
    const float* __restrict__ relp,          // [H]
    float* __restrict__ agg,                 // [TCHUNK*nDst, 128] (gelu applied)
    int nDst, int nSrc, int tBase) {
    int idx = blockIdx.x * 256 + threadIdx.x;
    int total = TCHUNK * nDst * NH * 8;
    if (idx >= total) return;
    int h = idx & 3;
    int slot = (idx >> 2) & 7;
    int node = (idx >> 5) % nDst;
    int tl = (idx >> 5) / nDst;
    int t = tBase + tl;

    size_t drow = (size_t)(tl * nDst + node);
    float p = relp[h] * 0.17677669529663687f;

    const float4* qp = (const float4*)(qD + drow * 128 + h * HD);
    float qr[HD];
#pragma unroll
    for (int j = 0; j < 8; j++) {
        float4 v = qp[j];
        qr[4 * j + 0] = v.x * p; qr[4 * j + 1] = v.y * p;
        qr[4 * j + 2] = v.z * p; qr[4 * j + 3] = v.w * p;
    }

    float m = -INFINITY, z = 0.f;
    float acc[HD];
#pragma unroll
    for (int d = 0; d < HD; d++) acc[d] = 0.f;

    int e0 = off[t * (nDst + 1) + node], e1 = off[t * (nDst + 1) + node + 1];
    const int* ssT = ssrc + (size_t)t * NE;

    for (int i = e0 + slot; i < e1; i += 8) {
        int s = ssT[i];
        const uint4* kp = (const uint4*)(kmS + ((size_t)(tl * nSrc + s)) * 256);
        uint ku[16], mu_[16];
        *(uint4*)(ku + 0) = kp[h * 4 + 0];
        *(uint4*)(ku + 4) = kp[h * 4 + 1];
        *(uint4*)(ku + 8) = kp[h * 4 + 2];
        *(uint4*)(ku + 12) = kp[h * 4 + 3];
        *(uint4*)(mu_ + 0) = kp[16 + h * 4 + 0];
        *(uint4*)(mu_ + 4) = kp[16 + h * 4 + 1];
        *(uint4*)(mu_ + 8) = kp[16 + h * 4 + 2];
        *(uint4*)(mu_ + 12) = kp[16 + h * 4 + 3];

        float dot = 0.f;
#pragma unroll
        for (int j = 0; j < 16; ++j) {
            float2 f = bf2x(ku[j]);
            dot = fmaf(qr[2 * j], f.x, dot);
            dot = fmaf(qr[2 * j + 1], f.y, dot);
        }
        float mn = fmaxf(m, dot);
        float c = __expf(m - mn);
        float w = __expf(dot - mn);
        z = z * c + w;
#pragma unroll
        for (int j = 0; j < 16; ++j) {
            float2 f = bf2x(mu_[j]);
            acc[2 * j] = fmaf(w, f.x, acc[2 * j] * c);
            acc[2 * j + 1] = fmaf(w, f.y, acc[2 * j + 1] * c);
        }
        m = mn;
    }

#pragma unroll
    for (int lm = 4; lm <= 16; lm <<= 1) {
        float mo = __shfl_xor(m, lm);
        float zo = __shfl_xor(z, lm);
        float mn = fmaxf(m, mo);
        float s1 = (m > -INFINITY) ? __expf(m - mn) : 0.f;
        float s2 = (mo > -INFINITY) ? __expf(mo - mn) : 0.f;
        z = z * s1 + zo * s2;
#pragma unroll
        for (int d = 0; d < HD; d++) {
            float ao = __shfl_xor(acc[d], lm);
            acc[d] = acc[d] * s1 + ao * s2;
        }
        m = mn;
    }

    if (slot == 0) {
        float inv = 1.f / (z + 1e-16f);
        float* op = agg + drow * CH + h * HD;
#pragma unroll
        for (int d = 0; d < HD; d++) {
            float v = acc[d] * inv;
            v = 0.5f * v * (1.f + erff(v * 0.70710678118654752f));  // fused exact gelu
            op[d] = v;
        }
    }
}

__global__ void gather_traj(const float* __restrict__ tkg, const int* __restrict__ traj,
                            const int* __restrict__ tki, float* __restrict__ outp) {
    int idx = blockIdx.x * blockDim.x + threadIdx.x;
    if (idx >= 64 * 128 * 128) return;
    int r = idx >> 7, c2 = idx & 127;
    int t = tki[r], n = traj[r];
    outp[idx] = tkg[((size_t)t * NLL + n) * CH + c2];
}

// ---------------- launch ----------------
extern "C" void kernel_launch(void* const* d_in, const int* in_sizes, int n_in,
                              void* d_out, int out_size, void* d_ws, size_t ws_size,
                              hipStream_t stream) {
    (void)in_sizes; (void)n_in; (void)out_size; (void)ws_size;
    const float* user_emb = (const float*)d_in[0];
    const float* loc_emb = (const float*)d_in[1];
    const float* lin_user_w = (const float*)d_in[2];
    const float* lin_user_b = (const float*)d_in[3];
    const float* lin_loc_w = (const float*)d_in[4];
    const float* lin_loc_b = (const float*)d_in[5];
    const float* w_user = (const float*)d_in[6];
    const float* b_user = (const float*)d_in[7];
    const float* w_loc = (const float*)d_in[8];
    const float* b_loc = (const float*)d_in[9];
    const float* rel_a = (const float*)d_in[10];
    const float* rel_m = (const float*)d_in[11];
    const float* rel_p = (const float*)d_in[12];
    const float* skip = (const float*)d_in[13];
    const float* lin2_w = (const float*)d_in[14];
    const float* lin2_b = (const float*)d_in[15];
    const int* user_ids = (const int*)d_in[16];
    const int* loc_ids = (const int*)d_in[17];
    const int* ei_ul_src = (const int*)d_in[18];
    const int* ei_ul_dst = (const int*)d_in[19];
    const int* ei_lu_src = (const int*)d_in[20];
    const int* ei_lu_dst = (const int*)d_in[21];
    const int* traj = (const int*)d_in[22];
    const int* tkg_idx = (const int*)d_in[23];
    float* outp = (float*)d_out;

    size_t woff = 0;
    char* base = (char*)d_ws;
    auto carve = [&](size_t bytes) -> void* {
        void* p = base + woff;
        woff += (bytes + 255) & ~(size_t)255;
        return p;
    };
    float* xu = (float*)carve((size_t)T_LEN * NUU * 128 * 4);
    float* xl = (float*)carve((size_t)T_LEN * NLL * 128 * 4);
    float* q_u = (float*)carve((size_t)TCHUNK * NUU * 128 * 4);
    float* q_l = (float*)carve((size_t)TCHUNK * NLL * 128 * 4);
    unsigned short* km_u = (unsigned short*)carve((size_t)TCHUNK * NUU * 256 * 2);
    unsigned short* km_l = (unsigned short*)carve((size_t)TCHUNK * NLL * 256 * 2);
    float* agg_u = (float*)carve((size_t)TCHUNK * NUU * 128 * 4);
    float* agg_l = (float*)carve((size_t)TCHUNK * NLL * 128 * 4);
    float* wf_u = (float*)carve(128 * 384 * 4);
    float* bf_u = (float*)carve(384 * 4);
    float* wf_l = (float*)carve(128 * 384 * 4);
    float* bf_l = (float*)carve(384 * 4);
    int* deg_ul = (int*)carve((size_t)T_LEN * NLL * 4);
    int* cur_ul = (int*)carve((size_t)T_LEN * NLL * 4);
    int* off_ul = (int*)carve((size_t)T_LEN * (NLL + 1) * 4);
    int* ss_ul = (int*)carve((size_t)T_LEN * NE * 4);
    int* deg_lu = (int*)carve((size_t)T_LEN * NUU * 4);
    int* cur_lu = (int*)carve((size_t)T_LEN * NUU * 4);
    int* off_lu = (int*)carve((size_t)T_LEN * (NUU + 1) * 4);
    int* ss_lu = (int*)carve((size_t)T_LEN * NE * 4);
    unsigned short* bp_lin_u = (unsigned short*)carve(128 * 512);
    unsigned short* bp_lin_l = (unsigned short*)carve(128 * 512);
    unsigned short* bp_lin2 = (unsigned short*)carve(128 * 512);
    unsigned short* bp_upd_u[2] = {(unsigned short*)carve(128 * 512), (unsigned short*)carve(128 * 512)};
    unsigned short* bp_upd_l[2] = {(unsigned short*)carve(128 * 512), (unsigned short*)carve(128 * 512)};
    unsigned short* bp_wf_u = (unsigned short*)carve(384 * 512);
    unsigned short* bp_wf_l = (unsigned short*)carve(384 * 512);

    // ---- CSR build ----
    fill_zero_int<<<cdiv(T_LEN * NLL, 256), 256, 0, stream>>>(deg_ul, T_LEN * NLL);
    fill_zero_int<<<cdiv(T_LEN * NUU, 256), 256, 0, stream>>>(deg_lu, T_LEN * NUU);
    histo_kernel<<<cdiv(T_LEN * NE, 256), 256, 0, stream>>>(ei_ul_dst, deg_ul, NLL);
    histo_kernel<<<cdiv(T_LEN * NE, 256), 256, 0, stream>>>(ei_lu_dst, deg_lu, NUU);
    scan_off<<<T_LEN, 256, 0, stream>>>(deg_ul, off_ul, cur_ul, NLL);
    scan_off<<<T_LEN, 256, 0, stream>>>(deg_lu, off_lu, cur_lu, NUU);
    scatter_src<<<cdiv(T_LEN * NE, 256), 256, 0, stream>>>(ei_ul_dst, ei_ul_src, cur_ul, ss_ul, NLL);
    scatter_src<<<cdiv(T_LEN * NE, 256), 256, 0, stream>>>(ei_lu_dst, ei_lu_src, cur_lu, ss_lu, NUU);

    // ---- weight preps ----
    bprep_kernel<<<64, 256, 0, stream>>>(lin_user_w, bp_lin_u, 128);
    bprep_kernel<<<64, 256, 0, stream>>>(lin_loc_w, bp_lin_l, 128);
    bprep_kernel<<<64, 256, 0, stream>>>(lin2_w, bp_lin2, 128);
    for (int l = 0; l < 2; ++l) {
        bprep_kernel<<<64, 256, 0, stream>>>(w_user + (size_t)(l * 4 + 3) * 16384, bp_upd_u[l], 128);
        bprep_kernel<<<64, 256, 0, stream>>>(w_loc + (size_t)(l * 4 + 3) * 16384, bp_upd_l[l], 128);
    }

    // ---- embed + linear + relu ----
    gemm_mfma<true, 1><<<dim3(cdiv(T_LEN * NUU, 128), 2), 256, 0, stream>>>(
        user_emb, user_ids, bp_lin_u, lin_user_b, xu, nullptr, nullptr, nullptr, T_LEN * NUU, 128);
    gemm_mfma<true, 1><<<dim3(cdiv(T_LEN * NLL, 128), 2), 256, 0, stream>>>(
        loc_emb, loc_ids, bp_lin_l, lin_loc_b, xl, nullptr, nullptr, nullptr, T_LEN * NLL, 128);

    // ---- HGT layers ----
    for (int l = 0; l < 2; ++l) {
        build_fused<<<cdiv(128 * 384, 256), 256, 0, stream>>>(
            w_user + (size_t)l * 4 * 16384, b_user + l * 512,
            rel_a + (size_t)(l * 2 + 0) * 4096, rel_m + (size_t)(l * 2 + 0) * 4096, wf_u, bf_u);
        build_fused<<<cdiv(128 * 384, 256), 256, 0, stream>>>(
            w_loc + (size_t)l * 4 * 16384, b_loc + l * 512,
            rel_a + (size_t)(l * 2 + 1) * 4096, rel_m + (size_t)(l * 2 + 1) * 4096, wf_l, bf_l);
        bprep_kernel<<<192, 256, 0, stream>>>(wf_u, bp_wf_u, 384);
        bprep_kernel<<<192, 256, 0, stream>>>(wf_l, bp_wf_l, 384);

        for (int tb = 0; tb < T_LEN; tb += TCHUNK) {
            const int MU = TCHUNK * NUU;   // 16000
            const int ML = TCHUNK * NLL;   // 40000
            float* xu_c = xu + (size_t)tb * NUU * 128;
            float* xl_c = xl + (size_t)tb * NLL * 128;

            gemm_mfma<false, 3><<<dim3(cdiv(MU, 128), 6), 256, 0, stream>>>(
                xu_c, nullptr, bp_wf_u, bf_u, q_u, nullptr, nullptr, km_u, MU, 384);
            gemm_mfma<false, 3><<<dim3(cdiv(ML, 128), 6), 256, 0, stream>>>(
                xl_c, nullptr, bp_wf_l, bf_l, q_l, nullptr, nullptr, km_l, ML, 384);

            agg_edges<<<cdiv(TCHUNK * NLL * NH * 8, 256), 256, 0, stream>>>(
                q_l, km_u, off_ul, ss_ul, rel_p + (l * 2 + 0) * 4, agg_l, NLL, NUU, tb);
            agg_edges<<<cdiv(TCHUNK * NUU * NH * 8, 256), 256, 0, stream>>>(
                q_u, km_l, off_lu, ss_lu, rel_p + (l * 2 + 1) * 4, agg_u, NUU, NLL, tb);

            gemm_mfma<false, 2><<<dim3(cdiv(MU, 128), 2), 256, 0, stream>>>(
                agg_u, nullptr, bp_upd_u[l], b_user + l * 512 + 384,
                xu_c, xu_c, skip + l * 2 + 0, nullptr, MU, 128);
            gemm_mfma<false, 2><<<dim3(cdiv(ML, 128), 2), 256, 0, stream>>>(
                agg_l, nullptr, bp_upd_l[l], b_loc + l * 512 + 384,
                xl_c, xl_c, skip + l * 2 + 1, nullptr, ML, 128);
        }
    }

    // ---- lin2 -> tkg_out region of d_out ----
    float* tkg_out = outp + (size_t)64 * 128 * 128;
    gemm_mfma<false, 0><<<dim3(cdiv(T_LEN * NLL, 128), 2), 256, 0, stream>>>(
        xl, nullptr, bp_lin2, lin2_b, tkg_out, nullptr, nullptr, nullptr, T_LEN * NLL, 128);

    // ---- trajectory gather ----
    gather_traj<<<cdiv(64 * 128 * 128, 256), 256, 0, stream>>>(tkg_out, traj, tkg_idx, outp);
}

// Round 8
// 1546.086 us; speedup vs baseline: 1.0730x; 1.0730x over previous
//
#include <hip/hip_runtime.h>
#include <math.h>

#define T_LEN 24
#define NUU 2000
#define NLL 5000
#define NE 40000
#define CH 128
#define NH 4
#define HD 32
#define TCHUNK 8

typedef __attribute__((ext_vector_type(8))) short short8;
typedef __attribute__((ext_vector_type(4))) float f32x4;

static inline int cdiv(int a, int b) { return (a + b - 1) / b; }

__device__ __forceinline__ unsigned short f2bf(float x) {
    unsigned u = __float_as_uint(x);
    unsigned r = (u + 0x7fff + ((u >> 16) & 1)) >> 16;  // RNE
    return (unsigned short)r;
}
__device__ __forceinline__ float bf2f(unsigned short h) {
    return __uint_as_float(((unsigned)h) << 16);
}
__device__ __forceinline__ float2 bf2x(unsigned u) {
    float2 r;
    r.x = __uint_as_float(u << 16);
    r.y = __uint_as_float(u & 0xffff0000u);
    return r;
}

// ---------------- CSR build ----------------
__global__ void fill_zero_int(int* __restrict__ p, int n) {
    int i = blockIdx.x * blockDim.x + threadIdx.x;
    if (i < n) p[i] = 0;
}

__global__ void histo_kernel(const int* __restrict__ dst, int* __restrict__ deg, int n) {
    int idx = blockIdx.x * blockDim.x + threadIdx.x;
    if (idx >= T_LEN * NE) return;
    int t = idx / NE;
    atomicAdd(&deg[t * n + dst[idx]], 1);
}

// scan: writes both off and cur (exclusive prefix cursor)
__global__ __launch_bounds__(256) void scan_off(const int* __restrict__ deg, int* __restrict__ offo,
                                                int* __restrict__ cur, int n) {
    __shared__ int part[256];
    int t = blockIdx.x, tid = threadIdx.x;
    int items = (n + 255) / 256;
    int start = tid * items, end = min(start + items, n);
    const int* dt = deg + t * n;
    int s = 0;
    for (int i = start; i < end; ++i) s += dt[i];
    part[tid] = s;
    __syncthreads();
    for (int d = 1; d < 256; d <<= 1) {
        int v = (tid >= d) ? part[tid - d] : 0;
        __syncthreads();
        part[tid] += v;
        __syncthreads();
    }
    int run = part[tid] - s;
    int* ot = offo + t * (n + 1);
    int* ct = cur + t * n;
    if (tid == 0) ot[0] = 0;
    for (int i = start; i < end; ++i) {
        ct[i] = run;
        run += dt[i];
        ot[i + 1] = run;
    }
}

// scatter src value directly into dst-sorted position
__global__ void scatter_src(const int* __restrict__ dst, const int* __restrict__ src,
                            int* __restrict__ cur, int* __restrict__ ssrc, int n) {
    int idx = blockIdx.x * blockDim.x + threadIdx.x;
    if (idx >= T_LEN * NE) return;
    int t = idx / NE;
    int d = dst[idx];
    int pos = atomicAdd(&cur[t * n + d], 1);
    ssrc[(size_t)t * NE + pos] = src[idx];
}

// ---------------- fused relation weights (f32) ----------------
__global__ __launch_bounds__(256) void build_fused(
    const float* __restrict__ w, const float* __restrict__ b,
    const float* __restrict__ ra, const float* __restrict__ rm,
    float* __restrict__ Wf, float* __restrict__ bf) {
    int idx = blockIdx.x * 256 + threadIdx.x;
    if (idx >= 128 * 384) return;
    int c = idx / 384, col = idx - c * 384;
    if (col < 128) {
        Wf[c * 384 + col] = w[16384 + c * 128 + col];
        if (c == 0) bf[col] = b[128 + col];
    } else {
        int sec = (col - 128) >> 7;
        int hc = (col - 128) & 127;
        int h = hc >> 5, e2 = hc & 31;
        const float* A = (sec == 0 ? ra : rm) + h * 1024;
        const float* wsrc = w + (sec == 0 ? 0 : 2) * 16384;
        const float* bsrc = b + (sec == 0 ? 0 : 2) * 128;
        float s = 0.f, sb = 0.f;
#pragma unroll
        for (int d = 0; d < 32; ++d) {
            float a = A[d * 32 + e2];
            s += wsrc[c * 128 + h * 32 + d] * a;
            sb += bsrc[h * 32 + d] * a;
        }
        Wf[c * 384 + col] = s;
        if (c == 0) bf[col] = sb;
    }
}

// ---------------- B prep ----------------
__global__ void bprep_kernel(const float* __restrict__ W, unsigned short* __restrict__ prep, int N) {
    int idx = blockIdx.x * blockDim.x + threadIdx.x;
    if (idx >= 128 * N) return;
    int k = idx / N, n = idx - k * N;
    float v = W[idx];
    unsigned short hi = f2bf(v);
    unsigned short lo = f2bf(v - bf2f(hi));
    int nt = n >> 6, nl = n & 63;
    size_t base = (size_t)nt * 16384 + (size_t)nl * 128 + k;
    prep[base] = hi;
    prep[base + 8192] = lo;
}

// ---------------- MFMA GEMM (unchanged from R6) ----------------
template <bool GATHER, int EPI>
__global__ __launch_bounds__(256) void gemm_mfma(
    const float* __restrict__ A, const int* __restrict__ ids,
    const unsigned short* __restrict__ prep, const float* __restrict__ bias,
    float* __restrict__ C, const float* __restrict__ Xold,
    const float* __restrict__ skipPtr, unsigned short* __restrict__ km,
    int M, int NC) {
    __shared__ __align__(16) char smem[65536];

    const int tid = threadIdx.x;
    const int lane = tid & 63;
    const int wid_w = tid >> 6;
    const int wm = wid_w >> 1, wn = wid_w & 1;
    const int l15 = lane & 15, l4 = lane >> 4;

    const int nx = gridDim.x, ny = gridDim.y;
    int flat = blockIdx.y * nx + blockIdx.x;
    int nwg = nx * ny;
    int q = nwg >> 3, r = nwg & 7;
    int xcd = flat & 7, rank = flat >> 3;
    int wgid = (xcd < r ? xcd * (q + 1) : r * (q + 1) + (xcd - r) * q) + rank;
    const int m0 = (wgid / ny) * 128;
    const int n0 = (wgid % ny) * 64;

    const unsigned short* bp = prep + (size_t)(wgid % ny) * 16384;
    short8 bh[2][4], bl[2][4];
#pragma unroll
    for (int nf = 0; nf < 2; ++nf) {
        int ncol = wn * 32 + nf * 16 + l15;
#pragma unroll
        for (int ks = 0; ks < 4; ++ks) {
            size_t off = (size_t)ncol * 128 + ks * 32 + l4 * 8;
            bh[nf][ks] = *(const short8*)(bp + off);
            bl[nf][ks] = *(const short8*)(bp + 8192 + off);
        }
    }

#pragma unroll
    for (int i = 0; i < 16; ++i) {
        int flat2 = i * 256 + tid;
        int rr = flat2 >> 5, c4 = flat2 & 31;
        int gr = m0 + rr;
        if (gr >= M) gr = M - 1;
        int arow = GATHER ? ids[gr] : gr;
        float4 v = *(const float4*)(A + (size_t)arow * 128 + c4 * 4);
        unsigned short h0 = f2bf(v.x), h1 = f2bf(v.y), h2 = f2bf(v.z), h3 = f2bf(v.w);
        unsigned short q0 = f2bf(v.x - bf2f(h0)), q1 = f2bf(v.y - bf2f(h1));
        unsigned short q2 = f2bf(v.z - bf2f(h2)), q3 = f2bf(v.w - bf2f(h3));
        uint2 hp, lp;
        hp.x = (unsigned)h0 | ((unsigned)h1 << 16);
        hp.y = (unsigned)h2 | ((unsigned)h3 << 16);
        lp.x = (unsigned)q0 | ((unsigned)q1 << 16);
        lp.y = (unsigned)q2 | ((unsigned)q3 << 16);
        int off = rr * 256 + ((c4 * 8) ^ ((rr & 7) << 4));
        *(uint2*)(smem + off) = hp;
        *(uint2*)(smem + 32768 + off) = lp;
    }
    __syncthreads();

    f32x4 acc[4][2];
#pragma unroll
    for (int m = 0; m < 4; ++m)
#pragma unroll
        for (int nf = 0; nf < 2; ++nf) acc[m][nf] = (f32x4)0.f;

#pragma unroll
    for (int ks = 0; ks < 4; ++ks) {
        short8 ah[4], al[4];
#pragma unroll
        for (int m = 0; m < 4; ++m) {
            int row = wm * 64 + m * 16 + l15;
            int off = row * 256 + ((ks * 64 + l4 * 16) ^ ((row & 7) << 4));
            ah[m] = *(const short8*)(smem + off);
            al[m] = *(const short8*)(smem + 32768 + off);
        }
#pragma unroll
        for (int m = 0; m < 4; ++m)
#pragma unroll
            for (int nf = 0; nf < 2; ++nf) {
                acc[m][nf] = __builtin_amdgcn_mfma_f32_16x16x32_bf16(al[m], bh[nf][ks], acc[m][nf], 0, 0, 0);
                acc[m][nf] = __builtin_amdgcn_mfma_f32_16x16x32_bf16(ah[m], bl[nf][ks], acc[m][nf], 0, 0, 0);
                acc[m][nf] = __builtin_amdgcn_mfma_f32_16x16x32_bf16(ah[m], bh[nf][ks], acc[m][nf], 0, 0, 0);
            }
    }

    float g = 0.f;
    if (EPI == 2) g = 1.f / (1.f + expf(-skipPtr[0]));
    float bias_v[2];
#pragma unroll
    for (int nf = 0; nf < 2; ++nf) bias_v[nf] = bias[n0 + wn * 32 + nf * 16 + l15];

#pragma unroll
    for (int m = 0; m < 4; ++m) {
#pragma unroll
        for (int nf = 0; nf < 2; ++nf) {
            int gc = n0 + wn * 32 + nf * 16 + l15;
#pragma unroll
            for (int i = 0; i < 4; ++i) {
                int gr = m0 + wm * 64 + m * 16 + l4 * 4 + i;
                if (gr >= M) continue;
                float x = acc[m][nf][i] + bias_v[nf];
                if (EPI == 1) x = fmaxf(x, 0.f);
                if (EPI == 2) {
                    float xo = Xold[(size_t)gr * NC + gc];
                    x = g * x + (1.f - g) * xo;
                }
                if (EPI == 3) {
                    if (gc < 128) C[(size_t)gr * 128 + gc] = x;
                    else km[(size_t)gr * 256 + (gc - 128)] = f2bf(x);
                } else {
                    C[(size_t)gr * NC + gc] = x;
                }
            }
        }
    }
}

// ---------------- edge aggregation core: 4 slots, pair-unrolled edge loop ----------------
__device__ __forceinline__ void agg_core(
    int idx, const float* __restrict__ qD, const unsigned short* __restrict__ kmS,
    const int* __restrict__ off, const int* __restrict__ ssrc,
    const float* __restrict__ relp, float* __restrict__ agg,
    int nDst, int nSrc, int tBase) {
    int h = idx & 3;
    int slot = (idx >> 2) & 3;
    int node = (idx >> 4) % nDst;
    int tl = (idx >> 4) / nDst;
    int t = tBase + tl;

    size_t drow = (size_t)(tl * nDst + node);
    float p = relp[h] * 0.17677669529663687f;

    const float4* qp = (const float4*)(qD + drow * 128 + h * HD);
    float qr[HD];
#pragma unroll
    for (int j = 0; j < 8; j++) {
        float4 v = qp[j];
        qr[4 * j + 0] = v.x * p; qr[4 * j + 1] = v.y * p;
        qr[4 * j + 2] = v.z * p; qr[4 * j + 3] = v.w * p;
    }

    float m = -INFINITY, z = 0.f;
    float acc[HD];
#pragma unroll
    for (int d = 0; d < HD; d++) acc[d] = 0.f;

    int e0 = off[t * (nDst + 1) + node], e1 = off[t * (nDst + 1) + node + 1];
    const int* ssT = ssrc + (size_t)t * NE;

    int i = e0 + slot;
    // pair-unrolled: issue both edges' loads before computing (2x memory-level parallelism)
    for (; i + 4 < e1; i += 8) {
        int s0 = ssT[i], s1 = ssT[i + 4];
        const uint4* kp0 = (const uint4*)(kmS + ((size_t)(tl * nSrc + s0)) * 256);
        const uint4* kp1 = (const uint4*)(kmS + ((size_t)(tl * nSrc + s1)) * 256);
        uint4 k0a = kp0[h * 4 + 0], k0b = kp0[h * 4 + 1], k0c = kp0[h * 4 + 2], k0d = kp0[h * 4 + 3];
        uint4 m0a = kp0[16 + h * 4 + 0], m0b = kp0[16 + h * 4 + 1], m0c = kp0[16 + h * 4 + 2], m0d = kp0[16 + h * 4 + 3];
        uint4 k1a = kp1[h * 4 + 0], k1b = kp1[h * 4 + 1], k1c = kp1[h * 4 + 2], k1d = kp1[h * 4 + 3];
        uint4 m1a = kp1[16 + h * 4 + 0], m1b = kp1[16 + h * 4 + 1], m1c = kp1[16 + h * 4 + 2], m1d = kp1[16 + h * 4 + 3];

        uint ku0[16], ku1[16], mu0[16], mu1[16];
        *(uint4*)(ku0 + 0) = k0a; *(uint4*)(ku0 + 4) = k0b; *(uint4*)(ku0 + 8) = k0c; *(uint4*)(ku0 + 12) = k0d;
        *(uint4*)(mu0 + 0) = m0a; *(uint4*)(mu0 + 4) = m0b; *(uint4*)(mu0 + 8) = m0c; *(uint4*)(mu0 + 12) = m0d;
        *(uint4*)(ku1 + 0) = k1a; *(uint4*)(ku1 + 4) = k1b; *(uint4*)(ku1 + 8) = k1c; *(uint4*)(ku1 + 12) = k1d;
        *(uint4*)(mu1 + 0) = m1a; *(uint4*)(mu1 + 4) = m1b; *(uint4*)(mu1 + 8) = m1c; *(uint4*)(mu1 + 12) = m1d;

        float dot0 = 0.f, dot1 = 0.f;
#pragma unroll
        for (int j = 0; j < 16; ++j) {
            float2 f0 = bf2x(ku0[j]);
            float2 f1 = bf2x(ku1[j]);
            dot0 = fmaf(qr[2 * j], f0.x, dot0);
            dot0 = fmaf(qr[2 * j + 1], f0.y, dot0);
            dot1 = fmaf(qr[2 * j], f1.x, dot1);
            dot1 = fmaf(qr[2 * j + 1], f1.y, dot1);
        }
        float mn = fmaxf(m, fmaxf(dot0, dot1));
        float c = __expf(m - mn);
        float w0 = __expf(dot0 - mn);
        float w1 = __expf(dot1 - mn);
        z = z * c + w0 + w1;
#pragma unroll
        for (int j = 0; j < 16; ++j) {
            float2 f0 = bf2x(mu0[j]);
            float2 f1 = bf2x(mu1[j]);
            acc[2 * j] = fmaf(w1, f1.x, fmaf(w0, f0.x, acc[2 * j] * c));
            acc[2 * j + 1] = fmaf(w1, f1.y, fmaf(w0, f0.y, acc[2 * j + 1] * c));
        }
        m = mn;
    }
    if (i < e1) {  // tail single edge
        int s = ssT[i];
        const uint4* kp = (const uint4*)(kmS + ((size_t)(tl * nSrc + s)) * 256);
        uint ku[16], mu_[16];
        *(uint4*)(ku + 0) = kp[h * 4 + 0];
        *(uint4*)(ku + 4) = kp[h * 4 + 1];
        *(uint4*)(ku + 8) = kp[h * 4 + 2];
        *(uint4*)(ku + 12) = kp[h * 4 + 3];
        *(uint4*)(mu_ + 0) = kp[16 + h * 4 + 0];
        *(uint4*)(mu_ + 4) = kp[16 + h * 4 + 1];
        *(uint4*)(mu_ + 8) = kp[16 + h * 4 + 2];
        *(uint4*)(mu_ + 12) = kp[16 + h * 4 + 3];
        float dot = 0.f;
#pragma unroll
        for (int j = 0; j < 16; ++j) {
            float2 f = bf2x(ku[j]);
            dot = fmaf(qr[2 * j], f.x, dot);
            dot = fmaf(qr[2 * j + 1], f.y, dot);
        }
        float mn = fmaxf(m, dot);
        float c = __expf(m - mn);
        float w = __expf(dot - mn);
        z = z * c + w;
#pragma unroll
        for (int j = 0; j < 16; ++j) {
            float2 f = bf2x(mu_[j]);
            acc[2 * j] = fmaf(w, f.x, acc[2 * j] * c);
            acc[2 * j + 1] = fmaf(w, f.y, acc[2 * j + 1] * c);
        }
        m = mn;
    }

    // merge 4 slot partials (lanes differ in bits [3:2])
#pragma unroll
    for (int lm = 4; lm <= 8; lm <<= 1) {
        float mo = __shfl_xor(m, lm);
        float zo = __shfl_xor(z, lm);
        float mn = fmaxf(m, mo);
        float s1 = (m > -INFINITY) ? __expf(m - mn) : 0.f;
        float s2 = (mo > -INFINITY) ? __expf(mo - mn) : 0.f;
        z = z * s1 + zo * s2;
#pragma unroll
        for (int d = 0; d < HD; d++) {
            float ao = __shfl_xor(acc[d], lm);
            acc[d] = acc[d] * s1 + ao * s2;
        }
        m = mn;
    }

    if (slot == 0) {
        float inv = 1.f / (z + 1e-16f);
        float* op = agg + drow * CH + h * HD;
#pragma unroll
        for (int d = 0; d < HD; d++) {
            float v = acc[d] * inv;
            v = 0.5f * v * (1.f + erff(v * 0.70710678118654752f));  // fused exact gelu
            op[d] = v;
        }
    }
}

// fused dual-direction aggregation: blocks [0, UL_B) do user->loc, the rest loc->user
#define UL_B ((TCHUNK * NLL * NH * 4) / 256)  // 2500
#define LU_B ((TCHUNK * NUU * NH * 4) / 256)  // 1000
__global__ __launch_bounds__(256) void agg_dual(
    const float* __restrict__ q_l, const unsigned short* __restrict__ km_u,
    const int* __restrict__ off_ul, const int* __restrict__ ss_ul,
    const float* __restrict__ relp_ul, float* __restrict__ agg_l,
    const float* __restrict__ q_u, const unsigned short* __restrict__ km_l,
    const int* __restrict__ off_lu, const int* __restrict__ ss_lu,
    const float* __restrict__ relp_lu, float* __restrict__ agg_u,
    int tBase) {
    if (blockIdx.x < UL_B) {
        int idx = blockIdx.x * 256 + threadIdx.x;
        agg_core(idx, q_l, km_u, off_ul, ss_ul, relp_ul, agg_l, NLL, NUU, tBase);
    } else {
        int idx = (blockIdx.x - UL_B) * 256 + threadIdx.x;
        agg_core(idx, q_u, km_l, off_lu, ss_lu, relp_lu, agg_u, NUU, NLL, tBase);
    }
}

__global__ void gather_traj(const float* __restrict__ tkg, const int* __restrict__ traj,
                            const int* __restrict__ tki, float* __restrict__ outp) {
    int idx = blockIdx.x * blockDim.x + threadIdx.x;
    if (idx >= 64 * 128 * 128) return;
    int r = idx >> 7, c2 = idx & 127;
    int t = tki[r], n = traj[r];
    outp[idx] = tkg[((size_t)t * NLL + n) * CH + c2];
}

// ---------------- launch ----------------
extern "C" void kernel_launch(void* const* d_in, const int* in_sizes, int n_in,
                              void* d_out, int out_size, void* d_ws, size_t ws_size,
                              hipStream_t stream) {
    (void)in_sizes; (void)n_in; (void)out_size; (void)ws_size;
    const float* user_emb = (const float*)d_in[0];
    const float* loc_emb = (const float*)d_in[1];
    const float* lin_user_w = (const float*)d_in[2];
    const float* lin_user_b = (const float*)d_in[3];
    const float* lin_loc_w = (const float*)d_in[4];
    const float* lin_loc_b = (const float*)d_in[5];
    const float* w_user = (const float*)d_in[6];
    const float* b_user = (const float*)d_in[7];
    const float* w_loc = (const float*)d_in[8];
    const float* b_loc = (const float*)d_in[9];
    const float* rel_a = (const float*)d_in[10];
    const float* rel_m = (const float*)d_in[11];
    const float* rel_p = (const float*)d_in[12];
    const float* skip = (const float*)d_in[13];
    const float* lin2_w = (const float*)d_in[14];
    const float* lin2_b = (const float*)d_in[15];
    const int* user_ids = (const int*)d_in[16];
    const int* loc_ids = (const int*)d_in[17];
    const int* ei_ul_src = (const int*)d_in[18];
    const int* ei_ul_dst = (const int*)d_in[19];
    const int* ei_lu_src = (const int*)d_in[20];
    const int* ei_lu_dst = (const int*)d_in[21];
    const int* traj = (const int*)d_in[22];
    const int* tkg_idx = (const int*)d_in[23];
    float* outp = (float*)d_out;

    size_t woff = 0;
    char* base = (char*)d_ws;
    auto carve = [&](size_t bytes) -> void* {
        void* p = base + woff;
        woff += (bytes + 255) & ~(size_t)255;
        return p;
    };
    float* xu = (float*)carve((size_t)T_LEN * NUU * 128 * 4);
    float* xl = (float*)carve((size_t)T_LEN * NLL * 128 * 4);
    float* q_u = (float*)carve((size_t)TCHUNK * NUU * 128 * 4);
    float* q_l = (float*)carve((size_t)TCHUNK * NLL * 128 * 4);
    unsigned short* km_u = (unsigned short*)carve((size_t)TCHUNK * NUU * 256 * 2);
    unsigned short* km_l = (unsigned short*)carve((size_t)TCHUNK * NLL * 256 * 2);
    float* agg_u = (float*)carve((size_t)TCHUNK * NUU * 128 * 4);
    float* agg_l = (float*)carve((size_t)TCHUNK * NLL * 128 * 4);
    float* wf_u = (float*)carve(128 * 384 * 4);
    float* bf_u = (float*)carve(384 * 4);
    float* wf_l = (float*)carve(128 * 384 * 4);
    float* bf_l = (float*)carve(384 * 4);
    int* deg_ul = (int*)carve((size_t)T_LEN * NLL * 4);
    int* cur_ul = (int*)carve((size_t)T_LEN * NLL * 4);
    int* off_ul = (int*)carve((size_t)T_LEN * (NLL + 1) * 4);
    int* ss_ul = (int*)carve((size_t)T_LEN * NE * 4);
    int* deg_lu = (int*)carve((size_t)T_LEN * NUU * 4);
    int* cur_lu = (int*)carve((size_t)T_LEN * NUU * 4);
    int* off_lu = (int*)carve((size_t)T_LEN * (NUU + 1) * 4);
    int* ss_lu = (int*)carve((size_t)T_LEN * NE * 4);
    unsigned short* bp_lin_u = (unsigned short*)carve(128 * 512);
    unsigned short* bp_lin_l = (unsigned short*)carve(128 * 512);
    unsigned short* bp_lin2 = (unsigned short*)carve(128 * 512);
    unsigned short* bp_upd_u[2] = {(unsigned short*)carve(128 * 512), (unsigned short*)carve(128 * 512)};
    unsigned short* bp_upd_l[2] = {(unsigned short*)carve(128 * 512), (unsigned short*)carve(128 * 512)};
    unsigned short* bp_wf_u = (unsigned short*)carve(384 * 512);
    unsigned short* bp_wf_l = (unsigned short*)carve(384 * 512);

    // ---- CSR build ----
    fill_zero_int<<<cdiv(T_LEN * NLL, 256), 256, 0, stream>>>(deg_ul, T_LEN * NLL);
    fill_zero_int<<<cdiv(T_LEN * NUU, 256), 256, 0, stream>>>(deg_lu, T_LEN * NUU);
    histo_kernel<<<cdiv(T_LEN * NE, 256), 256, 0, stream>>>(ei_ul_dst, deg_ul, NLL);
    histo_kernel<<<cdiv(T_LEN * NE, 256), 256, 0, stream>>>(ei_lu_dst, deg_lu, NUU);
    scan_off<<<T_LEN, 256, 0, stream>>>(deg_ul, off_ul, cur_ul, NLL);
    scan_off<<<T_LEN, 256, 0, stream>>>(deg_lu, off_lu, cur_lu, NUU);
    scatter_src<<<cdiv(T_LEN * NE, 256), 256, 0, stream>>>(ei_ul_dst, ei_ul_src, cur_ul, ss_ul, NLL);
    scatter_src<<<cdiv(T_LEN * NE, 256), 256, 0, stream>>>(ei_lu_dst, ei_lu_src, cur_lu, ss_lu, NUU);

    // ---- weight preps ----
    bprep_kernel<<<64, 256, 0, stream>>>(lin_user_w, bp_lin_u, 128);
    bprep_kernel<<<64, 256, 0, stream>>>(lin_loc_w, bp_lin_l, 128);
    bprep_kernel<<<64, 256, 0, stream>>>(lin2_w, bp_lin2, 128);
    for (int l = 0; l < 2; ++l) {
        bprep_kernel<<<64, 256, 0, stream>>>(w_user + (size_t)(l * 4 + 3) * 16384, bp_upd_u[l], 128);
        bprep_kernel<<<64, 256, 0, stream>>>(w_loc + (size_t)(l * 4 + 3) * 16384, bp_upd_l[l], 128);
    }

    // ---- embed + linear + relu ----
    gemm_mfma<true, 1><<<dim3(cdiv(T_LEN * NUU, 128), 2), 256, 0, stream>>>(
        user_emb, user_ids, bp_lin_u, lin_user_b, xu, nullptr, nullptr, nullptr, T_LEN * NUU, 128);
    gemm_mfma<true, 1><<<dim3(cdiv(T_LEN * NLL, 128), 2), 256, 0, stream>>>(
        loc_emb, loc_ids, bp_lin_l, lin_loc_b, xl, nullptr, nullptr, nullptr, T_LEN * NLL, 128);

    // ---- HGT layers ----
    for (int l = 0; l < 2; ++l) {
        build_fused<<<cdiv(128 * 384, 256), 256, 0, stream>>>(
            w_user + (size_t)l * 4 * 16384, b_user + l * 512,
            rel_a + (size_t)(l * 2 + 0) * 4096, rel_m + (size_t)(l * 2 + 0) * 4096, wf_u, bf_u);
        build_fused<<<cdiv(128 * 384, 256), 256, 0, stream>>>(
            w_loc + (size_t)l * 4 * 16384, b_loc + l * 512,
            rel_a + (size_t)(l * 2 + 1) * 4096, rel_m + (size_t)(l * 2 + 1) * 4096, wf_l, bf_l);
        bprep_kernel<<<192, 256, 0, stream>>>(wf_u, bp_wf_u, 384);
        bprep_kernel<<<192, 256, 0, stream>>>(wf_l, bp_wf_l, 384);

        for (int tb = 0; tb < T_LEN; tb += TCHUNK) {
            const int MU = TCHUNK * NUU;   // 16000
            const int ML = TCHUNK * NLL;   // 40000
            float* xu_c = xu + (size_t)tb * NUU * 128;
            float* xl_c = xl + (size_t)tb * NLL * 128;

            gemm_mfma<false, 3><<<dim3(cdiv(MU, 128), 6), 256, 0, stream>>>(
                xu_c, nullptr, bp_wf_u, bf_u, q_u, nullptr, nullptr, km_u, MU, 384);
            gemm_mfma<false, 3><<<dim3(cdiv(ML, 128), 6), 256, 0, stream>>>(
                xl_c, nullptr, bp_wf_l, bf_l, q_l, nullptr, nullptr, km_l, ML, 384);

            agg_dual<<<UL_B + LU_B, 256, 0, stream>>>(
                q_l, km_u, off_ul, ss_ul, rel_p + (l * 2 + 0) * 4, agg_l,
                q_u, km_l, off_lu, ss_lu, rel_p + (l * 2 + 1) * 4, agg_u, tb);

            gemm_mfma<false, 2><<<dim3(cdiv(MU, 128), 2), 256, 0, stream>>>(
                agg_u, nullptr, bp_upd_u[l], b_user + l * 512 + 384,
                xu_c, xu_c, skip + l * 2 + 0, nullptr, MU, 128);
            gemm_mfma<false, 2><<<dim3(cdiv(ML, 128), 2), 256, 0, stream>>>(
                agg_l, nullptr, bp_upd_l[l], b_loc + l * 512 + 384,
                xl_c, xl_c, skip + l * 2 + 1, nullptr, ML, 128);
        }
    }

    // ---- lin2 -> tkg_out region of d_out ----
    float* tkg_out = outp + (size_t)64 * 128 * 128;
    gemm_mfma<false, 0><<<dim3(cdiv(T_LEN * NLL, 128), 2), 256, 0, stream>>>(
        xl, nullptr, bp_lin2, lin2_b, tkg_out, nullptr, nullptr, nullptr, T_LEN * NLL, 128);

    // ---- trajectory gather ----
    gather_traj<<<cdiv(64 * 128 * 128, 256), 256, 0, stream>>>(tkg_out, traj, tkg_idx, outp);
}